// Round 6
// baseline (116.267 us; speedup 1.0000x reference)
//
#include <hip/hip_runtime.h>
#include <hip/hip_bf16.h>
#include <math.h>

#define TD 512      // D (feature dim)
#define TH 64       // H (hidden dim)
#define CHUNK 64    // rows per chunk
#define NT 512      // threads per block (8 waves)
#define NBLK 256    // flat main-kernel blocks (1 per CU)

typedef __attribute__((ext_vector_type(8))) short bf16x8;
typedef __attribute__((ext_vector_type(4))) float f32x4;

__device__ __forceinline__ unsigned short f2b(float f) {
    return __builtin_bit_cast(unsigned short, __float2bfloat16(f));
}

__device__ __forceinline__ float tanh_fast(float v) {
    float e = __expf(2.0f * v);
    return 1.0f - 2.0f / (e + 1.0f);
}

// Barrier that drains LDS ops only — global prefetch loads stay in flight.
__device__ __forceinline__ void barrier_lgkm() {
    asm volatile("s_waitcnt lgkmcnt(0)" ::: "memory");
    __builtin_amdgcn_s_barrier();
}

// Prep: segment offsets off[0..B] AND zero the output/denominator accumulators.
__global__ void prep_kernel(const int* __restrict__ batch32,
                            int* __restrict__ off,
                            float* __restrict__ outp,
                            float* __restrict__ denom,
                            int N, int B) {
    int i = blockIdx.x * blockDim.x + threadIdx.x;
    if (i < B * TD) outp[i] = 0.0f;
    if (i < B) denom[i] = 0.0f;
    if (i >= N) return;
    const bool is64 = (batch32[N - 1] == 0);   // int64 LE => word N-1 is a high word == 0
    auto bval = [&](int k) -> int { return is64 ? batch32[2 * k] : batch32[k]; };
    int bc = bval(i);
    if (i == 0) {
        for (int j = 0; j <= bc; ++j) off[j] = 0;
    } else {
        int bp = bval(i - 1);
        for (int j = bp + 1; j <= bc; ++j) off[j] = i;
    }
    if (i == N - 1) {
        for (int j = bc + 1; j <= B; ++j) off[j] = N;
    }
}

__global__ __launch_bounds__(NT, 2)
void attnpool_flat(const float* __restrict__ x,
                   const float* __restrict__ W1,
                   const float* __restrict__ b1,
                   const float* __restrict__ W2,
                   const float* __restrict__ b2,
                   const int* __restrict__ off,
                   float* __restrict__ outp,
                   float* __restrict__ denom,
                   int N, int B, int rpb)
{
    __shared__ __align__(16) unsigned short W1T[TH * TD];      // bf16 bits, [col][k], swizzled
    __shared__ __align__(16) unsigned short Atile[CHUNK * TD]; // bf16 bits, [row][k], swizzled
    __shared__ float sP[4][CHUNK];
    __shared__ float wbuf[CHUNK];
    __shared__ float b1s[TH];
    __shared__ float W2s[TH];

    const int tid  = threadIdx.x;
    const int lane = tid & 63;
    const int w    = tid >> 6;

    const int r0 = blockIdx.x * rpb;
    const int r1 = min(N, r0 + rpb);
    const int nrows = r1 - r0;
    if (nrows <= 0) return;   // whole block exits (no barriers crossed)
    const float b2v = b2[0];

    const int rowcls = tid >> 7;          // 0..3 (wave-pair uniform)
    const int col4   = (tid & 127) << 2;  // feature column base (x4)
    const int ct     = w >> 1;            // coltile 0..3
    const int rt0    = (w & 1) << 1;      // rowtile base (0 or 2)

    // segment containing r0
    int s_lo = 0, s_hi = B - 1;
    while (s_lo < s_hi) { int mid = (s_lo + s_hi) >> 1; if (off[mid + 1] <= r0) s_lo = mid + 1; else s_hi = mid; }
    int cur_seg = s_lo;
    int next_b  = off[cur_seg + 1];

    float4 accw; accw.x = 0.f; accw.y = 0.f; accw.z = 0.f; accw.w = 0.f;
    float d_acc = 0.0f;                   // per-lane denom partial (wave 0 only)
    float4 xrA[16], xrB[16];

    auto load_chunk = [&](float4 (&xr)[16], int c0) {
        #pragma unroll
        for (int p = 0; p < 16; ++p) {
            int rl = (p << 2) + rowcls;
            int r  = c0 + rl;
            int gr = (r < nrows) ? (r0 + r) : r0;   // clamp; pads get weight 0
            xr[p] = *reinterpret_cast<const float4*>(&x[(size_t)gr * TD + col4]);
        }
    };

    auto flush = [&]() {
        atomicAdd(&outp[(size_t)cur_seg * TD + col4 + 0], accw.x);
        atomicAdd(&outp[(size_t)cur_seg * TD + col4 + 1], accw.y);
        atomicAdd(&outp[(size_t)cur_seg * TD + col4 + 2], accw.z);
        atomicAdd(&outp[(size_t)cur_seg * TD + col4 + 3], accw.w);
        accw.x = 0.f; accw.y = 0.f; accw.z = 0.f; accw.w = 0.f;
        if (w == 0) {
            float s = d_acc;
            #pragma unroll
            for (int m = 1; m < 64; m <<= 1) s += __shfl_xor(s, m, 64);
            if (lane == 0) atomicAdd(&denom[cur_seg], s);
            d_acc = 0.0f;
        }
    };

    // issue first x-chunk loads ASAP, then stage W1 while they fly
    load_chunk(xrA, 0);

    for (int i = 0; i < (TH * TD) / NT; ++i) {   // 64 iters
        int e = tid + NT * i;          // flat index into W1 [k][j]
        int k = e >> 6;
        int j = e & 63;
        W1T[(j * TD + k) ^ ((j & 7) << 3)] = f2b(W1[e]);
    }
    if (tid < TH) { b1s[tid] = b1[tid]; W2s[tid] = W2[tid]; }
    barrier_lgkm();   // W1T/b1s/W2s ready; x loads remain in flight

    auto body = [&](float4 (&cur)[16], float4 (&nxt)[16], int c0) {
        // (1) prefetch FIRST; loads stay outstanding across barriers below
        if (c0 + CHUNK < nrows) load_chunk(nxt, c0 + CHUNK);

        // (2) convert + store A tile (swizzled)
        #pragma unroll
        for (int p = 0; p < 16; ++p) {
            int rl = (p << 2) + rowcls;
            ushort4 v;
            v.x = f2b(cur[p].x); v.y = f2b(cur[p].y);
            v.z = f2b(cur[p].z); v.w = f2b(cur[p].w);
            *reinterpret_cast<ushort4*>(&Atile[(rl * TD + col4) ^ ((rl & 7) << 3)]) = v;
        }
        barrier_lgkm();   // #1: Atile ready (no vmcnt drain)

        // (3) MFMA: wave covers rowtiles rt0,rt0+1 x coltile ct, full K
        f32x4 acc0 = {0,0,0,0}, acc1 = {0,0,0,0};
        const int kb = (lane >> 4) << 3;
        {
            const int rA = (rt0 << 4) + (lane & 15);
            const int rB = rA + 16;
            const int cc = (ct << 4) + (lane & 15);
            #pragma unroll
            for (int kk = 0; kk < 16; ++kk) {
                int k0 = (kk << 5) + kb;
                bf16x8 bf = *reinterpret_cast<const bf16x8*>(&W1T[(cc * TD + k0) ^ ((cc & 7) << 3)]);
                bf16x8 a0 = *reinterpret_cast<const bf16x8*>(&Atile[(rA * TD + k0) ^ ((rA & 7) << 3)]);
                bf16x8 a1 = *reinterpret_cast<const bf16x8*>(&Atile[(rB * TD + k0) ^ ((rB & 7) << 3)]);
                acc0 = __builtin_amdgcn_mfma_f32_16x16x32_bf16(a0, bf, acc0, 0, 0, 0);
                acc1 = __builtin_amdgcn_mfma_f32_16x16x32_bf16(a1, bf, acc1, 0, 0, 0);
            }
        }
        // (4) bias + tanh + *W2, reduce over this wave's 16 cols, write sP
        {
            const int j = (ct << 4) + (lane & 15);
            float pa[4], pb[4];
            #pragma unroll
            for (int q = 0; q < 4; ++q) {
                pa[q] = tanh_fast(acc0[q] + b1s[j]) * W2s[j];
                pb[q] = tanh_fast(acc1[q] + b1s[j]) * W2s[j];
            }
            #pragma unroll
            for (int m = 1; m < 16; m <<= 1) {
                #pragma unroll
                for (int q = 0; q < 4; ++q) {
                    pa[q] += __shfl_xor(pa[q], m, 64);
                    pb[q] += __shfl_xor(pb[q], m, 64);
                }
            }
            if ((lane & 15) == 0) {
                int g = lane >> 4;
                #pragma unroll
                for (int q = 0; q < 4; ++q) {
                    sP[ct][(rt0 << 4) + (g << 2) + q]      = pa[q];
                    sP[ct][(rt0 << 4) + 16 + (g << 2) + q] = pb[q];
                }
            }
        }
        barrier_lgkm();   // #2: sP ready

        // (5) wave 0: direct exp (|s| <= sum|W2|+|b2| ~ 4.3 -> no max needed)
        if (w == 0) {
            float s = sP[0][lane] + sP[1][lane] + sP[2][lane] + sP[3][lane] + b2v;
            wbuf[lane] = __expf(s);
        }
        barrier_lgkm();   // #3: wbuf ready

        // (6) segment-aware weighted accumulation (multi-pass only at boundaries)
        const int base = r0 + c0;
        const int cend = min(CHUNK, nrows - c0);
        int plo = 0;
        while (plo < cend) {
            int phi = next_b - base; if (phi > cend) phi = cend;   // rows of cur_seg
            #pragma unroll
            for (int p = 0; p < 16; ++p) {
                int rl = (p << 2) + rowcls;
                float wgt = (rl >= plo && rl < phi) ? wbuf[rl] : 0.0f;
                accw.x += wgt * cur[p].x;
                accw.y += wgt * cur[p].y;
                accw.z += wgt * cur[p].z;
                accw.w += wgt * cur[p].w;
            }
            if (w == 0) d_acc += (lane >= plo && lane < phi) ? wbuf[lane] : 0.0f;
            if (phi < cend) {   // boundary strictly inside chunk
                flush();
                int rn = base + phi;
                while (off[cur_seg + 1] <= rn) ++cur_seg;
                next_b = off[cur_seg + 1];
            }
            plo = phi;
        }
        // boundary exactly at chunk end (with more rows to come)
        if (c0 + CHUNK < nrows && next_b == base + cend) {
            flush();
            int rn = base + cend;
            while (off[cur_seg + 1] <= rn) ++cur_seg;
            next_b = off[cur_seg + 1];
        }
    };

    int c0 = 0;
    while (true) {
        body(xrA, xrB, c0);
        c0 += CHUNK;
        if (c0 >= nrows) break;
        body(xrB, xrA, c0);
        c0 += CHUNK;
        if (c0 >= nrows) break;
    }
    flush();   // residual for the last segment
}

// Normalize: out = partials / (denom + eps)
__global__ void norm_kernel(float* __restrict__ outp,
                            const float* __restrict__ denom, int total) {
    int i = blockIdx.x * blockDim.x + threadIdx.x;
    if (i < total) outp[i] = outp[i] / (denom[i >> 9] + 1e-16f);   // TD=512
}

extern "C" void kernel_launch(void* const* d_in, const int* in_sizes, int n_in,
                              void* d_out, int out_size, void* d_ws, size_t ws_size,
                              hipStream_t stream) {
    const float* x  = (const float*)d_in[0];
    const float* W1 = (const float*)d_in[1];
    const float* b1 = (const float*)d_in[2];
    const float* W2 = (const float*)d_in[3];
    const float* b2 = (const float*)d_in[4];
    const int* batch = (const int*)d_in[5];
    int N = in_sizes[5];
    int B = out_size / TD;
    if (B <= 0 || N <= 0) return;

    int*   off   = (int*)d_ws;                                  // B+1 ints
    float* denom = (float*)((char*)d_ws + (((B + 1) * 4 + 255) & ~255));  // B floats
    float* outp  = (float*)d_out;

    int rpb = (N + NBLK - 1) / NBLK;
    int prep_elems = (B * TD > N) ? B * TD : N;
    prep_kernel<<<dim3((prep_elems + 255) / 256), dim3(256), 0, stream>>>(
        batch, off, outp, denom, N, B);
    attnpool_flat<<<dim3(NBLK), dim3(NT), 0, stream>>>(
        x, W1, b1, W2, b2, off, outp, denom, N, B, rpb);
    norm_kernel<<<dim3((B * TD + 255) / 256), dim3(256), 0, stream>>>(
        outp, denom, B * TD);
}